// Round 1
// baseline (345.756 us; speedup 1.0000x reference)
//
#include <hip/hip_runtime.h>
#include <math.h>

#define NHID 1024
#define NPC  225
#define NCLS 224
#define BATCH 1024
#define N_TOP (BATCH / 8)       // 128

// ws float-offsets
#define WS_PT 0                 // float pt[1024]
#define WS_PB 1024              // float pb[1024]

// ---------------------------------------------------------------------------
// Fused kernel: blocks 0..223 = bottom softmax (one class each, self-grouped
// by scanning labels); blocks 224..351 = top softmax (8 samples each).
// 1024 threads = 16 waves; wave w covers d-rows [64w, 64w+64).
// ---------------------------------------------------------------------------
__global__ __launch_bounds__(1024, 4) void k_fused(const float* __restrict__ X,
                                                   const int* __restrict__ labels,
                                                   const float* __restrict__ Wt,
                                                   const float* __restrict__ bt,
                                                   const float* __restrict__ Wb,
                                                   const float* __restrict__ bb,
                                                   float* __restrict__ ws)
{
    __shared__ __align__(16) float sm[14848]; // in_t[256][48] / red[8][8][232]
    __shared__ int slist[128];
    __shared__ int scnt;

    const int tid  = threadIdx.x;
    const int wave = tid >> 6;
    const int lane = tid & 63;
    const int j8   = tid & 7;   // staging sample slot (constant per thread)
    const int t8   = tid >> 3;

    if ((int)blockIdx.x < NCLS) {
        // ------------------- bottom path: one block per class -------------------
        const int cls = blockIdx.x;
        if (tid == 0) scnt = 0;
        __syncthreads();
        {
            const int lab = labels[tid];
            if (lab / NPC == cls) {
                const int p = atomicAdd(&scnt, 1);
                if (p < 128) slist[p] = tid;
            }
        }
        __syncthreads();
        const int cnt = scnt;
        if (cnt == 0) return;

        const int c0 = lane, c1 = lane + 64, c2 = lane + 128, c3 = lane + 192;
        const bool m3 = (c3 < NPC);
        const int d0 = wave * 64;
        const float* Wr = Wb + (size_t)cls * (NHID * NPC) + (size_t)d0 * NPC;

        for (int base = 0; base < cnt; base += 8) {
            const int nt = min(8, cnt - base);

            // stage nt rows of X transposed, j-inner lane mapping
            const int sid = (j8 < nt) ? slist[base + j8] : -1;
            for (int d4 = t8; d4 < 256; d4 += 128) {
                float4 v = make_float4(0.f, 0.f, 0.f, 0.f);
                if (sid >= 0) v = ((const float4*)&X[(size_t)sid * NHID])[d4];
                float* p = &sm[48 * d4 + j8];
                p[0] = v.x; p[12] = v.y; p[24] = v.z; p[36] = v.w;
            }
            __syncthreads();

            float acc[8][4];
#pragma unroll
            for (int j = 0; j < 8; ++j)
#pragma unroll
                for (int k = 0; k < 4; ++k) acc[j][k] = 0.f;

            auto ldrow = [&](int r, float* o) {
                const float* p = Wr + (size_t)r * NPC;
                o[0] = __builtin_nontemporal_load(p + c0);
                o[1] = __builtin_nontemporal_load(p + c1);
                o[2] = __builtin_nontemporal_load(p + c2);
                o[3] = m3 ? __builtin_nontemporal_load(p + c3) : 0.f;
            };
            float wbuf[4][4];
            ldrow(0, wbuf[0]); ldrow(1, wbuf[1]); ldrow(2, wbuf[2]); ldrow(3, wbuf[3]);

#pragma unroll 4
            for (int dd = 0; dd < 64; ++dd) {
                const int slot = dd & 3;
                const float cw0 = wbuf[slot][0], cw1 = wbuf[slot][1],
                            cw2 = wbuf[slot][2], cw3 = wbuf[slot][3];
                ldrow(min(dd + 4, 63), wbuf[slot]);   // clamped tail re-read
                const float4 a = *(const float4*)&sm[(d0 + dd) * 12 + 0];
                const float4 b = *(const float4*)&sm[(d0 + dd) * 12 + 4];
                const float xi[8] = {a.x, a.y, a.z, a.w, b.x, b.y, b.z, b.w};
#pragma unroll
                for (int j = 0; j < 8; ++j) {
                    acc[j][0] = fmaf(xi[j], cw0, acc[j][0]);
                    acc[j][1] = fmaf(xi[j], cw1, acc[j][1]);
                    acc[j][2] = fmaf(xi[j], cw2, acc[j][2]);
                    acc[j][3] = fmaf(xi[j], cw3, acc[j][3]);
                }
            }
            __syncthreads();   // all waves done reading staging

            float* red = sm;   // red[(g*8 + j)*232 + c]
            if (wave >= 8) {
#pragma unroll
                for (int j = 0; j < 8; ++j)
#pragma unroll
                    for (int k = 0; k < 4; ++k) {
                        int c = lane + 64 * k;
                        if (c < NPC) red[((wave - 8) * 8 + j) * 232 + c] = acc[j][k];
                    }
            }
            __syncthreads();
            if (wave < 8) {
#pragma unroll
                for (int j = 0; j < 8; ++j)
#pragma unroll
                    for (int k = 0; k < 4; ++k) {
                        int c = lane + 64 * k;
                        if (c < NPC) red[(wave * 8 + j) * 232 + c] += acc[j][k];
                    }
            }
            __syncthreads();

            if (wave < 8) {
                const int j = wave;
                if (j < nt) {
                    const int s = slist[base + j];
                    float v[4];
#pragma unroll
                    for (int k = 0; k < 4; ++k) {
                        int c = lane + 64 * k;
                        if (c < NPC) {
                            float t = bb[(size_t)cls * NPC + c];
#pragma unroll
                            for (int g = 0; g < 8; ++g) t += red[(g * 8 + j) * 232 + c];
                            v[k] = t;
                        } else v[k] = -INFINITY;
                    }
                    float m = fmaxf(fmaxf(v[0], v[1]), fmaxf(v[2], v[3]));
                    for (int o = 32; o > 0; o >>= 1) m = fmaxf(m, __shfl_xor(m, o));
                    float e = expf(v[0] - m) + expf(v[1] - m) + expf(v[2] - m) + expf(v[3] - m);
                    for (int o = 32; o > 0; o >>= 1) e += __shfl_xor(e, o);
                    const int pb = labels[s] % NPC;
                    if (lane == (pb & 63))
                        ws[WS_PB + s] = expf(v[pb >> 6] - m) / e;
                }
            }
            __syncthreads();   // before next pass reuses sm
        }
        return;
    }

    // ------------------------------ top path ------------------------------
    const int sbase = (blockIdx.x - NCLS) * 8;

    for (int d4 = t8; d4 < 256; d4 += 128) {
        const float4 v = ((const float4*)&X[(size_t)(sbase + j8) * NHID])[d4];
        float* p = &sm[48 * d4 + j8];
        p[0] = v.x; p[12] = v.y; p[24] = v.z; p[36] = v.w;
    }
    __syncthreads();

    float acc[8][4];
#pragma unroll
    for (int j = 0; j < 8; ++j)
#pragma unroll
        for (int k = 0; k < 4; ++k) acc[j][k] = 0.f;

    const int c0 = lane, c1 = lane + 64, c2 = lane + 128, c3 = lane + 192;
    const bool m3 = (c3 < NCLS);
    const int d0 = wave * 64;
    const float* Wr = Wt + (size_t)d0 * NCLS;

    auto ldrow = [&](int r, float* o) {
        const float* p = Wr + (size_t)r * NCLS;
        o[0] = p[c0]; o[1] = p[c1]; o[2] = p[c2];
        o[3] = m3 ? p[c3] : 0.f;
    };
    float wbuf[4][4];
    ldrow(0, wbuf[0]); ldrow(1, wbuf[1]); ldrow(2, wbuf[2]); ldrow(3, wbuf[3]);

#pragma unroll 4
    for (int dd = 0; dd < 64; ++dd) {
        const int slot = dd & 3;
        const float cw0 = wbuf[slot][0], cw1 = wbuf[slot][1],
                    cw2 = wbuf[slot][2], cw3 = wbuf[slot][3];
        ldrow(min(dd + 4, 63), wbuf[slot]);
        const float4 a = *(const float4*)&sm[(d0 + dd) * 12 + 0];
        const float4 b = *(const float4*)&sm[(d0 + dd) * 12 + 4];
        const float xi[8] = {a.x, a.y, a.z, a.w, b.x, b.y, b.z, b.w};
#pragma unroll
        for (int j = 0; j < 8; ++j) {
            acc[j][0] = fmaf(xi[j], cw0, acc[j][0]);
            acc[j][1] = fmaf(xi[j], cw1, acc[j][1]);
            acc[j][2] = fmaf(xi[j], cw2, acc[j][2]);
            acc[j][3] = fmaf(xi[j], cw3, acc[j][3]);
        }
    }
    __syncthreads();

    float* red = sm;
    if (wave >= 8) {
#pragma unroll
        for (int j = 0; j < 8; ++j)
#pragma unroll
            for (int k = 0; k < 4; ++k) {
                int c = lane + 64 * k;
                if (c < NCLS) red[((wave - 8) * 8 + j) * 232 + c] = acc[j][k];
            }
    }
    __syncthreads();
    if (wave < 8) {
#pragma unroll
        for (int j = 0; j < 8; ++j)
#pragma unroll
            for (int k = 0; k < 4; ++k) {
                int c = lane + 64 * k;
                if (c < NCLS) red[(wave * 8 + j) * 232 + c] += acc[j][k];
            }
    }
    __syncthreads();

    if (wave < 8) {
        const int j = wave;
        const int s = sbase + j;
        float v[4];
#pragma unroll
        for (int k = 0; k < 4; ++k) {
            int c = lane + 64 * k;
            if (c < NCLS) {
                float t = bt[c];
#pragma unroll
                for (int g = 0; g < 8; ++g) t += red[(g * 8 + j) * 232 + c];
                v[k] = t;
            } else v[k] = -INFINITY;
        }
        float m = fmaxf(fmaxf(v[0], v[1]), fmaxf(v[2], v[3]));
        for (int o = 32; o > 0; o >>= 1) m = fmaxf(m, __shfl_xor(m, o));
        float e = expf(v[0] - m) + expf(v[1] - m) + expf(v[2] - m) + expf(v[3] - m);
        for (int o = 32; o > 0; o >>= 1) e += __shfl_xor(e, o);
        const int pt = labels[s] / NPC;
        if (lane == (pt & 63))
            ws[WS_PT + s] = expf(v[pt >> 6] - m) / e;
    }
}

// ---------------------------------------------------------------------------
// Finalize: out[s] = pt[s] * pb[s]
// ---------------------------------------------------------------------------
__global__ void k_mul(const float* __restrict__ ws, float* __restrict__ out)
{
    const int i = blockIdx.x * 256 + threadIdx.x;
    if (i < BATCH) out[i] = ws[WS_PT + i] * ws[WS_PB + i];
}

// ---------------------------------------------------------------------------
extern "C" void kernel_launch(void* const* d_in, const int* in_sizes, int n_in,
                              void* d_out, int out_size, void* d_ws, size_t ws_size,
                              hipStream_t stream)
{
    const float* X      = (const float*)d_in[0];
    const int*   labels = (const int*)  d_in[1];
    const float* Wt     = (const float*)d_in[2];
    const float* bt     = (const float*)d_in[3];
    const float* Wb     = (const float*)d_in[4];
    const float* bb     = (const float*)d_in[5];

    hipLaunchKernelGGL(k_fused, dim3(NCLS + N_TOP), dim3(1024), 0, stream,
                       X, labels, Wt, bt, Wb, bb, (float*)d_ws);
    hipLaunchKernelGGL(k_mul, dim3(BATCH / 256), dim3(256), 0, stream,
                       (const float*)d_ws, (float*)d_out);
}

// Round 2
// 304.100 us; speedup vs baseline: 1.1370x; 1.1370x over previous
//
#include <hip/hip_runtime.h>
#include <math.h>

#define NHID 1024
#define NPC  225
#define NCLS 224
#define BATCH 1024
#define N_BOT 352               // max bottom items = sum ceil(cnt/8)
#define N_TOP (BATCH / 8)       // 128

// ws float-offsets
#define WS_PT 0                 // float pt[1024]
#define WS_PB 1024              // float pb[1024]

// ---------------------------------------------------------------------------
// Fused kernel: blocks 0..351 = bottom softmax, ITEM granularity (<=8 samples
// of one class each); every bottom block self-groups (histogram + scan over
// the 1024 labels, ~2us, fully parallel across blocks -> no serial grouping
// pass, no k1->k2 dependency). Blocks 352..479 = top softmax (8 samples each),
// overlapping under the bottom stream's HBM shadow.
// 1024 threads = 16 waves; wave w covers d-rows [64w, 64w+64).
// ---------------------------------------------------------------------------
__global__ __launch_bounds__(1024, 4) void k_fused(const float* __restrict__ X,
                                                   const int* __restrict__ labels,
                                                   const float* __restrict__ Wt,
                                                   const float* __restrict__ bt,
                                                   const float* __restrict__ Wb,
                                                   const float* __restrict__ bb,
                                                   float* __restrict__ ws)
{
    __shared__ __align__(16) float sm[14848]; // in_t[256][48] / red[8][8][232]
    __shared__ int cnt_[256];
    __shared__ int iscan_[256];
    __shared__ int slot[8];
    __shared__ int wtot[16];
    __shared__ int cls_sh;

    const int tid  = threadIdx.x;
    const int wave = tid >> 6;
    const int lane = tid & 63;
    const int j8   = tid & 7;   // staging sample slot (constant per thread)
    const int t8   = tid >> 3;

    if ((int)blockIdx.x < N_BOT) {
        // ------------- self-grouping: locate this block's item -------------
        if (tid < 256) cnt_[tid] = 0;
        __syncthreads();
        const int myc = labels[tid] / NPC;          // tid < 1024 == BATCH
        atomicAdd(&cnt_[myc], 1);
        __syncthreads();
        if (tid < 256) iscan_[tid] = (tid < NCLS) ? ((cnt_[tid] + 7) >> 3) : 0;
        __syncthreads();
        for (int off = 1; off < 256; off <<= 1) {   // inclusive scan, 8 steps
            int a = 0;
            if (tid < 256 && tid >= off) a = iscan_[tid - off];
            __syncthreads();
            if (tid < 256) iscan_[tid] += a;
            __syncthreads();
        }
        if ((int)blockIdx.x >= iscan_[255]) return; // beyond nitems
        if (tid < NCLS) {                           // unique writer finds class
            const int lo = (tid == 0) ? 0 : iscan_[tid - 1];
            if ((int)blockIdx.x >= lo && (int)blockIdx.x < iscan_[tid]) cls_sh = tid;
        }
        __syncthreads();
        const int cls    = cls_sh;
        const int ibase  = (cls == 0) ? 0 : iscan_[cls - 1];
        const int within = (int)blockIdx.x - ibase; // item index inside class
        const int cnt    = cnt_[cls];
        const int nt     = min(8, cnt - 8 * within);

        // deterministic compaction: ballot order == sample-index order, so
        // every block of this class derives the identical sample->item map
        {
            const bool flag = (myc == cls);
            const unsigned long long m = __ballot(flag);
            if (lane == 0) wtot[wave] = __popcll(m);
            __syncthreads();
            if (flag) {
                int pos = __popcll(m & ((1ull << lane) - 1));
#pragma unroll
                for (int w = 0; w < 16; ++w)
                    if (w < wave) pos += wtot[w];
                const int r = pos - 8 * within;
                if (r >= 0 && r < 8) slot[r] = tid;
            }
            __syncthreads();
        }

        // ------------------- proven bottom inner loop -----------------------
        const int sid = (j8 < nt) ? slot[j8] : -1;
        for (int d4 = t8; d4 < 256; d4 += 128) {
            float4 v = make_float4(0.f, 0.f, 0.f, 0.f);
            if (sid >= 0) v = ((const float4*)&X[(size_t)sid * NHID])[d4];
            float* p = &sm[48 * d4 + j8];
            p[0] = v.x; p[12] = v.y; p[24] = v.z; p[36] = v.w;
        }
        __syncthreads();

        float acc[8][4];
#pragma unroll
        for (int j = 0; j < 8; ++j)
#pragma unroll
            for (int k = 0; k < 4; ++k) acc[j][k] = 0.f;

        const int c0 = lane, c1 = lane + 64, c2 = lane + 128, c3 = lane + 192;
        const bool m3 = (c3 < NPC);
        const int d0 = wave * 64;
        const float* Wr = Wb + (size_t)cls * (NHID * NPC) + (size_t)d0 * NPC;

        auto ldrow = [&](int r, float* o) {
            const float* p = Wr + (size_t)r * NPC;
            o[0] = __builtin_nontemporal_load(p + c0);
            o[1] = __builtin_nontemporal_load(p + c1);
            o[2] = __builtin_nontemporal_load(p + c2);
            o[3] = m3 ? __builtin_nontemporal_load(p + c3) : 0.f;
        };
        float wbuf[4][4];
        ldrow(0, wbuf[0]); ldrow(1, wbuf[1]); ldrow(2, wbuf[2]); ldrow(3, wbuf[3]);

#pragma unroll 4
        for (int dd = 0; dd < 64; ++dd) {
            const int slot4 = dd & 3;
            const float cw0 = wbuf[slot4][0], cw1 = wbuf[slot4][1],
                        cw2 = wbuf[slot4][2], cw3 = wbuf[slot4][3];
            ldrow(min(dd + 4, 63), wbuf[slot4]);   // clamped tail re-read
            const float4 a = *(const float4*)&sm[(d0 + dd) * 12 + 0];
            const float4 b = *(const float4*)&sm[(d0 + dd) * 12 + 4];
            const float xi[8] = {a.x, a.y, a.z, a.w, b.x, b.y, b.z, b.w};
#pragma unroll
            for (int j = 0; j < 8; ++j) {
                acc[j][0] = fmaf(xi[j], cw0, acc[j][0]);
                acc[j][1] = fmaf(xi[j], cw1, acc[j][1]);
                acc[j][2] = fmaf(xi[j], cw2, acc[j][2]);
                acc[j][3] = fmaf(xi[j], cw3, acc[j][3]);
            }
        }
        __syncthreads();   // all waves done reading staging

        float* red = sm;   // red[(g*8 + j)*232 + c]
        if (wave >= 8) {
#pragma unroll
            for (int j = 0; j < 8; ++j)
#pragma unroll
                for (int k = 0; k < 4; ++k) {
                    int c = lane + 64 * k;
                    if (c < NPC) red[((wave - 8) * 8 + j) * 232 + c] = acc[j][k];
                }
        }
        __syncthreads();
        if (wave < 8) {
#pragma unroll
            for (int j = 0; j < 8; ++j)
#pragma unroll
                for (int k = 0; k < 4; ++k) {
                    int c = lane + 64 * k;
                    if (c < NPC) red[(wave * 8 + j) * 232 + c] += acc[j][k];
                }
        }
        __syncthreads();

        if (wave < 8) {
            const int j = wave;
            if (j < nt) {
                const int s = slot[j];
                float v[4];
#pragma unroll
                for (int k = 0; k < 4; ++k) {
                    int c = lane + 64 * k;
                    if (c < NPC) {
                        float t = bb[(size_t)cls * NPC + c];
#pragma unroll
                        for (int g = 0; g < 8; ++g) t += red[(g * 8 + j) * 232 + c];
                        v[k] = t;
                    } else v[k] = -INFINITY;
                }
                float m = fmaxf(fmaxf(v[0], v[1]), fmaxf(v[2], v[3]));
                for (int o = 32; o > 0; o >>= 1) m = fmaxf(m, __shfl_xor(m, o));
                float e = expf(v[0] - m) + expf(v[1] - m) + expf(v[2] - m) + expf(v[3] - m);
                for (int o = 32; o > 0; o >>= 1) e += __shfl_xor(e, o);
                const int pb = labels[s] % NPC;
                if (lane == (pb & 63))
                    ws[WS_PB + s] = expf(v[pb >> 6] - m) / e;
            }
        }
        return;
    }

    // ------------------------------ top path ------------------------------
    const int sbase = ((int)blockIdx.x - N_BOT) * 8;

    for (int d4 = t8; d4 < 256; d4 += 128) {
        const float4 v = ((const float4*)&X[(size_t)(sbase + j8) * NHID])[d4];
        float* p = &sm[48 * d4 + j8];
        p[0] = v.x; p[12] = v.y; p[24] = v.z; p[36] = v.w;
    }
    __syncthreads();

    float acc[8][4];
#pragma unroll
    for (int j = 0; j < 8; ++j)
#pragma unroll
        for (int k = 0; k < 4; ++k) acc[j][k] = 0.f;

    const int c0 = lane, c1 = lane + 64, c2 = lane + 128, c3 = lane + 192;
    const bool m3 = (c3 < NCLS);
    const int d0 = wave * 64;
    const float* Wr = Wt + (size_t)d0 * NCLS;

    auto ldrow = [&](int r, float* o) {
        const float* p = Wr + (size_t)r * NCLS;
        o[0] = p[c0]; o[1] = p[c1]; o[2] = p[c2];
        o[3] = m3 ? p[c3] : 0.f;
    };
    float wbuf[4][4];
    ldrow(0, wbuf[0]); ldrow(1, wbuf[1]); ldrow(2, wbuf[2]); ldrow(3, wbuf[3]);

#pragma unroll 4
    for (int dd = 0; dd < 64; ++dd) {
        const int slot4 = dd & 3;
        const float cw0 = wbuf[slot4][0], cw1 = wbuf[slot4][1],
                    cw2 = wbuf[slot4][2], cw3 = wbuf[slot4][3];
        ldrow(min(dd + 4, 63), wbuf[slot4]);
        const float4 a = *(const float4*)&sm[(d0 + dd) * 12 + 0];
        const float4 b = *(const float4*)&sm[(d0 + dd) * 12 + 4];
        const float xi[8] = {a.x, a.y, a.z, a.w, b.x, b.y, b.z, b.w};
#pragma unroll
        for (int j = 0; j < 8; ++j) {
            acc[j][0] = fmaf(xi[j], cw0, acc[j][0]);
            acc[j][1] = fmaf(xi[j], cw1, acc[j][1]);
            acc[j][2] = fmaf(xi[j], cw2, acc[j][2]);
            acc[j][3] = fmaf(xi[j], cw3, acc[j][3]);
        }
    }
    __syncthreads();

    float* red = sm;
    if (wave >= 8) {
#pragma unroll
        for (int j = 0; j < 8; ++j)
#pragma unroll
            for (int k = 0; k < 4; ++k) {
                int c = lane + 64 * k;
                if (c < NCLS) red[((wave - 8) * 8 + j) * 232 + c] = acc[j][k];
            }
    }
    __syncthreads();
    if (wave < 8) {
#pragma unroll
        for (int j = 0; j < 8; ++j)
#pragma unroll
            for (int k = 0; k < 4; ++k) {
                int c = lane + 64 * k;
                if (c < NCLS) red[(wave * 8 + j) * 232 + c] += acc[j][k];
            }
    }
    __syncthreads();

    if (wave < 8) {
        const int j = wave;
        const int s = sbase + j;
        float v[4];
#pragma unroll
        for (int k = 0; k < 4; ++k) {
            int c = lane + 64 * k;
            if (c < NCLS) {
                float t = bt[c];
#pragma unroll
                for (int g = 0; g < 8; ++g) t += red[(g * 8 + j) * 232 + c];
                v[k] = t;
            } else v[k] = -INFINITY;
        }
        float m = fmaxf(fmaxf(v[0], v[1]), fmaxf(v[2], v[3]));
        for (int o = 32; o > 0; o >>= 1) m = fmaxf(m, __shfl_xor(m, o));
        float e = expf(v[0] - m) + expf(v[1] - m) + expf(v[2] - m) + expf(v[3] - m);
        for (int o = 32; o > 0; o >>= 1) e += __shfl_xor(e, o);
        const int pt = labels[s] / NPC;
        if (lane == (pt & 63))
            ws[WS_PT + s] = expf(v[pt >> 6] - m) / e;
    }
}

// ---------------------------------------------------------------------------
// Finalize: out[s] = pt[s] * pb[s]
// ---------------------------------------------------------------------------
__global__ void k_mul(const float* __restrict__ ws, float* __restrict__ out)
{
    const int i = blockIdx.x * 256 + threadIdx.x;
    if (i < BATCH) out[i] = ws[WS_PT + i] * ws[WS_PB + i];
}

// ---------------------------------------------------------------------------
extern "C" void kernel_launch(void* const* d_in, const int* in_sizes, int n_in,
                              void* d_out, int out_size, void* d_ws, size_t ws_size,
                              hipStream_t stream)
{
    const float* X      = (const float*)d_in[0];
    const int*   labels = (const int*)  d_in[1];
    const float* Wt     = (const float*)d_in[2];
    const float* bt     = (const float*)d_in[3];
    const float* Wb     = (const float*)d_in[4];
    const float* bb     = (const float*)d_in[5];

    hipLaunchKernelGGL(k_fused, dim3(N_BOT + N_TOP), dim3(1024), 0, stream,
                       X, labels, Wt, bt, Wb, bb, (float*)d_ws);
    hipLaunchKernelGGL(k_mul, dim3(BATCH / 256), dim3(256), 0, stream,
                       (const float*)d_ws, (float*)d_out);
}